// Round 1
// baseline (275.178 us; speedup 1.0000x reference)
//
#include <hip/hip_runtime.h>
#include <math.h>

#define VOCAB 50257
#define DIM 768
#define RANK 16
#define SCALING 2.0f   // ALPHA / RANK = 32/16

constexpr int P1_BLOCKS = 2048;
constexpr int P1_THREADS = 192;                                     // 3 waves; each thread owns 4 columns
constexpr int ROWS_PER_BLOCK = (VOCAB + P1_BLOCKS - 1) / P1_BLOCKS; // 25
constexpr int RED_THREADS = 256;
constexpr int RED_COLS = 16;                 // columns per reduce block
constexpr int RED_BLOCKS = DIM / RED_COLS;   // 48
constexpr int TOKENS_PER_BLOCK = 8;
constexpr int G_THREADS = 192;

// ---------------- Pass 1: per-block partial column sum-of-squares ----------------
// partials layout: [P1_BLOCKS][DIM] row-major. Every slot written (zeros for empty blocks).
// v2: rows processed in chunks of 2 with all loads issued before compute -> 2 KB in
// flight per wave instead of 1 KB, half the loop-carried latency exposure.
__global__ __launch_bounds__(P1_THREADS) void dora_pass1(
    const float* __restrict__ emb, const float* __restrict__ lora_a,
    const float* __restrict__ lora_b, float* __restrict__ partials) {
  const int t = threadIdx.x;     // 0..191
  const int c4 = t * 4;          // base column of this thread's float4 group

  // B[:, c4..c4+3] in registers: 16 x float4 = 64 VGPRs
  float4 B[RANK];
#pragma unroll
  for (int k = 0; k < RANK; ++k)
    B[k] = *reinterpret_cast<const float4*>(lora_b + k * DIM + c4);

  const int r0 = blockIdx.x * ROWS_PER_BLOCK;
  const int rcnt = min(ROWS_PER_BLOCK, VOCAB - r0);   // may be <= 0 for tail blocks

  const float* __restrict__ ebase = emb + (size_t)r0 * DIM + c4;
  const float* __restrict__ abase = lora_a + (size_t)r0 * RANK;   // wave-uniform -> scalar loads

  float4 acc = make_float4(0.f, 0.f, 0.f, 0.f);

  int i = 0;
  for (; i + 2 <= rcnt; i += 2) {
    // issue all memory for the chunk first
    const float4 e0 = *reinterpret_cast<const float4*>(ebase + (size_t)i * DIM);
    const float4 e1 = *reinterpret_cast<const float4*>(ebase + (size_t)(i + 1) * DIM);
    float a0[RANK], a1[RANK];
#pragma unroll
    for (int k = 0; k < RANK; ++k) a0[k] = abase[(size_t)i * RANK + k];
#pragma unroll
    for (int k = 0; k < RANK; ++k) a1[k] = abase[(size_t)(i + 1) * RANK + k];

    float d0x = 0.f, d0y = 0.f, d0z = 0.f, d0w = 0.f;
    float d1x = 0.f, d1y = 0.f, d1z = 0.f, d1w = 0.f;
#pragma unroll
    for (int k = 0; k < RANK; ++k) {
      d0x = fmaf(a0[k], B[k].x, d0x);
      d0y = fmaf(a0[k], B[k].y, d0y);
      d0z = fmaf(a0[k], B[k].z, d0z);
      d0w = fmaf(a0[k], B[k].w, d0w);
      d1x = fmaf(a1[k], B[k].x, d1x);
      d1y = fmaf(a1[k], B[k].y, d1y);
      d1z = fmaf(a1[k], B[k].z, d1z);
      d1w = fmaf(a1[k], B[k].w, d1w);
    }
    const float c0x = fmaf(SCALING, d0x, e0.x);
    const float c0y = fmaf(SCALING, d0y, e0.y);
    const float c0z = fmaf(SCALING, d0z, e0.z);
    const float c0w = fmaf(SCALING, d0w, e0.w);
    acc.x = fmaf(c0x, c0x, acc.x);
    acc.y = fmaf(c0y, c0y, acc.y);
    acc.z = fmaf(c0z, c0z, acc.z);
    acc.w = fmaf(c0w, c0w, acc.w);
    const float c1x = fmaf(SCALING, d1x, e1.x);
    const float c1y = fmaf(SCALING, d1y, e1.y);
    const float c1z = fmaf(SCALING, d1z, e1.z);
    const float c1w = fmaf(SCALING, d1w, e1.w);
    acc.x = fmaf(c1x, c1x, acc.x);
    acc.y = fmaf(c1y, c1y, acc.y);
    acc.z = fmaf(c1z, c1z, acc.z);
    acc.w = fmaf(c1w, c1w, acc.w);
  }
  // odd-row tail (rcnt = 25 for full blocks, 7 for the last partial block)
  if (i < rcnt) {
    const float4 e = *reinterpret_cast<const float4*>(ebase + (size_t)i * DIM);
    float dx = 0.f, dy = 0.f, dz = 0.f, dw = 0.f;
#pragma unroll
    for (int k = 0; k < RANK; ++k) {
      const float a = abase[(size_t)i * RANK + k];
      dx = fmaf(a, B[k].x, dx);
      dy = fmaf(a, B[k].y, dy);
      dz = fmaf(a, B[k].z, dz);
      dw = fmaf(a, B[k].w, dw);
    }
    const float cx = fmaf(SCALING, dx, e.x);
    const float cy = fmaf(SCALING, dy, e.y);
    const float cz = fmaf(SCALING, dz, e.z);
    const float cw = fmaf(SCALING, dw, e.w);
    acc.x = fmaf(cx, cx, acc.x);
    acc.y = fmaf(cy, cy, acc.y);
    acc.z = fmaf(cz, cz, acc.z);
    acc.w = fmaf(cw, cw, acc.w);
  }
  *reinterpret_cast<float4*>(partials + (size_t)blockIdx.x * DIM + c4) = acc;
}

// ---------------- Reduce: coalesced column reduction ----------------
// v2: each block owns 16 consecutive columns. Thread t -> col = t&15, row-group = t>>4.
// A wave-load now covers 4 rows x 64 B contiguous segments (fully-used cache lines)
// instead of 64 distinct lines per load in v1 (per-lane stride was 3072 B).
__global__ __launch_bounds__(RED_THREADS) void dora_reduce(
    const float* __restrict__ partials, const float* __restrict__ magnitude,
    float* __restrict__ scale) {
  const int t = threadIdx.x;                 // 0..255
  const int col = t & (RED_COLS - 1);        // 0..15
  const int rgrp = t >> 4;                   // 0..15
  const int c = blockIdx.x * RED_COLS + col;

  float s = 0.f;
#pragma unroll 8
  for (int r = rgrp; r < P1_BLOCKS; r += RED_THREADS / RED_COLS)  // 128 iters, 8 in flight
    s += partials[(size_t)r * DIM + c];

  // lanes {x, x^16, x^32, x^48} share a column -> butterfly over bits 4,5
  s += __shfl_xor(s, 16);
  s += __shfl_xor(s, 32);

  __shared__ float lds[RED_THREADS / 64][RED_COLS];
  const int wave = t >> 6;
  if ((t & 63) < RED_COLS) lds[wave][t & 63] = s;
  __syncthreads();
  if (t < RED_COLS) {
    float tot = lds[0][t] + lds[1][t] + lds[2][t] + lds[3][t];
    const float norm = fmaxf(sqrtf(tot), 1e-8f);
    const int cc = blockIdx.x * RED_COLS + t;
    scale[cc] = magnitude[cc] / norm;
  }
}

// ---------------- Gather: 8 tokens per block, batched row prefetch ----------------
// v2: fast path loads all 8 ids then issues all 8 emb-row loads (8 KB in flight per
// wave) before any compute; no per-iteration break to block pipelining.
__global__ __launch_bounds__(G_THREADS) void dora_gather(
    const int* __restrict__ tokens, const float* __restrict__ emb,
    const float* __restrict__ lora_a, const float* __restrict__ lora_b,
    const float* __restrict__ scale, float* __restrict__ out, int n_tokens) {
  const int t = threadIdx.x;
  const int c4 = t * 4;

  float4 B[RANK];
#pragma unroll
  for (int k = 0; k < RANK; ++k)
    B[k] = *reinterpret_cast<const float4*>(lora_b + k * DIM + c4);
  const float4 sc = *reinterpret_cast<const float4*>(scale + c4);

  const int tok0 = blockIdx.x * TOKENS_PER_BLOCK;

  if (tok0 + TOKENS_PER_BLOCK <= n_tokens) {
    // ---- fast path: all 8 tokens valid ----
    int ids[TOKENS_PER_BLOCK];
#pragma unroll
    for (int i = 0; i < TOKENS_PER_BLOCK; ++i) ids[i] = tokens[tok0 + i];  // wave-uniform

    float4 e[TOKENS_PER_BLOCK];
#pragma unroll
    for (int i = 0; i < TOKENS_PER_BLOCK; ++i)
      e[i] = *reinterpret_cast<const float4*>(emb + (size_t)ids[i] * DIM + c4);

#pragma unroll
    for (int i = 0; i < TOKENS_PER_BLOCK; ++i) {
      const float* __restrict__ arow = lora_a + (size_t)ids[i] * RANK;  // scalar loads
      float dx = 0.f, dy = 0.f, dz = 0.f, dw = 0.f;
#pragma unroll
      for (int k = 0; k < RANK; ++k) {
        const float a = arow[k];
        dx = fmaf(a, B[k].x, dx);
        dy = fmaf(a, B[k].y, dy);
        dz = fmaf(a, B[k].z, dz);
        dw = fmaf(a, B[k].w, dw);
      }
      float4 o;
      o.x = fmaf(SCALING, dx, e[i].x) * sc.x;
      o.y = fmaf(SCALING, dy, e[i].y) * sc.y;
      o.z = fmaf(SCALING, dz, e[i].z) * sc.z;
      o.w = fmaf(SCALING, dw, e[i].w) * sc.w;
      *reinterpret_cast<float4*>(out + (size_t)(tok0 + i) * DIM + c4) = o;
    }
  } else {
    // ---- tail path ----
    for (int i = 0; i < TOKENS_PER_BLOCK; ++i) {
      const int tok = tok0 + i;
      if (tok >= n_tokens) break;
      const int id = tokens[tok];
      const float* __restrict__ arow = lora_a + (size_t)id * RANK;
      const float4 ev = *reinterpret_cast<const float4*>(emb + (size_t)id * DIM + c4);
      float dx = 0.f, dy = 0.f, dz = 0.f, dw = 0.f;
#pragma unroll
      for (int k = 0; k < RANK; ++k) {
        const float a = arow[k];
        dx = fmaf(a, B[k].x, dx);
        dy = fmaf(a, B[k].y, dy);
        dz = fmaf(a, B[k].z, dz);
        dw = fmaf(a, B[k].w, dw);
      }
      float4 o;
      o.x = fmaf(SCALING, dx, ev.x) * sc.x;
      o.y = fmaf(SCALING, dy, ev.y) * sc.y;
      o.z = fmaf(SCALING, dz, ev.z) * sc.z;
      o.w = fmaf(SCALING, dw, ev.w) * sc.w;
      *reinterpret_cast<float4*>(out + (size_t)tok * DIM + c4) = o;
    }
  }
}

extern "C" void kernel_launch(void* const* d_in, const int* in_sizes, int n_in,
                              void* d_out, int out_size, void* d_ws, size_t ws_size,
                              hipStream_t stream) {
  const int*   tokens    = (const int*)d_in[0];    // [8,2048] int32
  const float* emb       = (const float*)d_in[1];  // [V, D]
  const float* lora_a    = (const float*)d_in[2];  // [V, R]
  const float* lora_b    = (const float*)d_in[3];  // [R, D]
  const float* magnitude = (const float*)d_in[4];  // [D]
  float* out = (float*)d_out;

  const int n_tokens = in_sizes[0];                // 16384

  float* partials = (float*)d_ws;                                  // P1_BLOCKS * DIM floats
  float* scale    = (float*)d_ws + (size_t)P1_BLOCKS * DIM;        // DIM floats

  dora_pass1<<<P1_BLOCKS, P1_THREADS, 0, stream>>>(emb, lora_a, lora_b, partials);
  dora_reduce<<<RED_BLOCKS, RED_THREADS, 0, stream>>>(partials, magnitude, scale);

  const int gather_blocks = (n_tokens + TOKENS_PER_BLOCK - 1) / TOKENS_PER_BLOCK;
  dora_gather<<<gather_blocks, G_THREADS, 0, stream>>>(tokens, emb, lora_a, lora_b,
                                                       scale, out, n_tokens);
}

// Round 2
// 266.857 us; speedup vs baseline: 1.0312x; 1.0312x over previous
//
#include <hip/hip_runtime.h>
#include <math.h>

#define VOCAB 50257
#define DIM 768
#define RANK 16
#define SCALING 2.0f   // ALPHA / RANK = 32/16

constexpr int P1_BLOCKS = 1024;
constexpr int P1_THREADS = 192;                                     // 3 waves; each thread owns 4 columns
constexpr int ROWS_PER_BLOCK = (VOCAB + P1_BLOCKS - 1) / P1_BLOCKS; // 50
constexpr int RED_THREADS = 256;
constexpr int RED_COLS = 16;                 // columns per reduce block
constexpr int RED_BLOCKS = DIM / RED_COLS;   // 48
constexpr int TOKENS_PER_BLOCK = 8;
constexpr int G_THREADS = 192;

// ---------------- Pass 1: per-block partial column sum-of-squares ----------------
// v3: __launch_bounds__(192,4) pins VGPR<=128 -> guaranteed 4 waves/SIMD (16/CU).
// 4-row chunks, all four float4 emb loads issued before any FMA -> 4 KB in flight
// per wave, >=48 KB per CU: 5x the ~9.2 KB needed to cover ~900cy HBM latency at
// the per-CU share of peak BW. Grid halved to 1024 blocks (50 rows each) so the
// 49 KB per-block B-preload is amortized over 2x the work.
__global__ __launch_bounds__(P1_THREADS, 4) void dora_pass1(
    const float* __restrict__ emb, const float* __restrict__ lora_a,
    const float* __restrict__ lora_b, float* __restrict__ partials) {
  const int t = threadIdx.x;     // 0..191
  const int c4 = t * 4;          // base column of this thread's float4 group

  // B[:, c4..c4+3] in registers: 16 x float4 = 64 VGPRs
  float4 B[RANK];
#pragma unroll
  for (int k = 0; k < RANK; ++k)
    B[k] = *reinterpret_cast<const float4*>(lora_b + k * DIM + c4);

  const int r0 = blockIdx.x * ROWS_PER_BLOCK;
  const int rcnt = min(ROWS_PER_BLOCK, VOCAB - r0);   // may be <= 0 for tail blocks

  const float* __restrict__ ebase = emb + (size_t)r0 * DIM + c4;
  const float* __restrict__ abase = lora_a + (size_t)r0 * RANK;   // wave-uniform -> scalar loads

  float4 acc = make_float4(0.f, 0.f, 0.f, 0.f);

  int i = 0;
  for (; i + 4 <= rcnt; i += 4) {
    // issue all vector memory for the chunk first (4 x 16 B per thread in flight)
    float4 e[4];
#pragma unroll
    for (int r = 0; r < 4; ++r)
      e[r] = *reinterpret_cast<const float4*>(ebase + (size_t)(i + r) * DIM);

    float4 d[4];
#pragma unroll
    for (int r = 0; r < 4; ++r) d[r] = make_float4(0.f, 0.f, 0.f, 0.f);

#pragma unroll
    for (int k = 0; k < RANK; ++k) {
#pragma unroll
      for (int r = 0; r < 4; ++r) {
        const float a = abase[(size_t)(i + r) * RANK + k];   // SGPR broadcast loads
        d[r].x = fmaf(a, B[k].x, d[r].x);
        d[r].y = fmaf(a, B[k].y, d[r].y);
        d[r].z = fmaf(a, B[k].z, d[r].z);
        d[r].w = fmaf(a, B[k].w, d[r].w);
      }
    }
#pragma unroll
    for (int r = 0; r < 4; ++r) {
      const float cx = fmaf(SCALING, d[r].x, e[r].x);
      const float cy = fmaf(SCALING, d[r].y, e[r].y);
      const float cz = fmaf(SCALING, d[r].z, e[r].z);
      const float cw = fmaf(SCALING, d[r].w, e[r].w);
      acc.x = fmaf(cx, cx, acc.x);
      acc.y = fmaf(cy, cy, acc.y);
      acc.z = fmaf(cz, cz, acc.z);
      acc.w = fmaf(cw, cw, acc.w);
    }
  }
  // tail rows (50257 = 1024*49 + ...; last live block has a short count)
  for (; i < rcnt; ++i) {
    const float4 ev = *reinterpret_cast<const float4*>(ebase + (size_t)i * DIM);
    float dx = 0.f, dy = 0.f, dz = 0.f, dw = 0.f;
#pragma unroll
    for (int k = 0; k < RANK; ++k) {
      const float a = abase[(size_t)i * RANK + k];
      dx = fmaf(a, B[k].x, dx);
      dy = fmaf(a, B[k].y, dy);
      dz = fmaf(a, B[k].z, dz);
      dw = fmaf(a, B[k].w, dw);
    }
    const float cx = fmaf(SCALING, dx, ev.x);
    const float cy = fmaf(SCALING, dy, ev.y);
    const float cz = fmaf(SCALING, dz, ev.z);
    const float cw = fmaf(SCALING, dw, ev.w);
    acc.x = fmaf(cx, cx, acc.x);
    acc.y = fmaf(cy, cy, acc.y);
    acc.z = fmaf(cz, cz, acc.z);
    acc.w = fmaf(cw, cw, acc.w);
  }
  // every block writes its slot (zeros for idle tail blocks) -> no ws zero-init needed
  *reinterpret_cast<float4*>(partials + (size_t)blockIdx.x * DIM + c4) = acc;
}

// ---------------- Reduce: coalesced column reduction ----------------
// Each block owns 16 consecutive columns. Thread t -> col = t&15, row-group = t>>4.
// A wave-load covers 4 rows x 64 B fully-used contiguous segments.
__global__ __launch_bounds__(RED_THREADS) void dora_reduce(
    const float* __restrict__ partials, const float* __restrict__ magnitude,
    float* __restrict__ scale) {
  const int t = threadIdx.x;                 // 0..255
  const int col = t & (RED_COLS - 1);        // 0..15
  const int rgrp = t >> 4;                   // 0..15
  const int c = blockIdx.x * RED_COLS + col;

  float s = 0.f;
#pragma unroll 8
  for (int r = rgrp; r < P1_BLOCKS; r += RED_THREADS / RED_COLS)  // 64 iters, 8 in flight
    s += partials[(size_t)r * DIM + c];

  // lanes {x, x^16, x^32, x^48} share a column -> butterfly over bits 4,5
  s += __shfl_xor(s, 16);
  s += __shfl_xor(s, 32);

  __shared__ float lds[RED_THREADS / 64][RED_COLS];
  const int wave = t >> 6;
  if ((t & 63) < RED_COLS) lds[wave][t & 63] = s;
  __syncthreads();
  if (t < RED_COLS) {
    float tot = lds[0][t] + lds[1][t] + lds[2][t] + lds[3][t];
    const float norm = fmaxf(sqrtf(tot), 1e-8f);
    const int cc = blockIdx.x * RED_COLS + t;
    scale[cc] = magnitude[cc] / norm;
  }
}

// ---------------- Gather: 8 tokens per block, batched row prefetch ----------------
// v3: __launch_bounds__(192,4) pins VGPR<=128 (B 64 + e[8] 32 + ids/sc ~ 120) so the
// 8-deep row prefetch no longer costs occupancy.
__global__ __launch_bounds__(G_THREADS, 4) void dora_gather(
    const int* __restrict__ tokens, const float* __restrict__ emb,
    const float* __restrict__ lora_a, const float* __restrict__ lora_b,
    const float* __restrict__ scale, float* __restrict__ out, int n_tokens) {
  const int t = threadIdx.x;
  const int c4 = t * 4;

  float4 B[RANK];
#pragma unroll
  for (int k = 0; k < RANK; ++k)
    B[k] = *reinterpret_cast<const float4*>(lora_b + k * DIM + c4);
  const float4 sc = *reinterpret_cast<const float4*>(scale + c4);

  const int tok0 = blockIdx.x * TOKENS_PER_BLOCK;

  if (tok0 + TOKENS_PER_BLOCK <= n_tokens) {
    // ---- fast path: all 8 tokens valid ----
    int ids[TOKENS_PER_BLOCK];
#pragma unroll
    for (int i = 0; i < TOKENS_PER_BLOCK; ++i) ids[i] = tokens[tok0 + i];  // wave-uniform

    float4 e[TOKENS_PER_BLOCK];
#pragma unroll
    for (int i = 0; i < TOKENS_PER_BLOCK; ++i)
      e[i] = *reinterpret_cast<const float4*>(emb + (size_t)ids[i] * DIM + c4);

#pragma unroll
    for (int i = 0; i < TOKENS_PER_BLOCK; ++i) {
      const float* __restrict__ arow = lora_a + (size_t)ids[i] * RANK;  // scalar loads
      float dx = 0.f, dy = 0.f, dz = 0.f, dw = 0.f;
#pragma unroll
      for (int k = 0; k < RANK; ++k) {
        const float a = arow[k];
        dx = fmaf(a, B[k].x, dx);
        dy = fmaf(a, B[k].y, dy);
        dz = fmaf(a, B[k].z, dz);
        dw = fmaf(a, B[k].w, dw);
      }
      float4 o;
      o.x = fmaf(SCALING, dx, e[i].x) * sc.x;
      o.y = fmaf(SCALING, dy, e[i].y) * sc.y;
      o.z = fmaf(SCALING, dz, e[i].z) * sc.z;
      o.w = fmaf(SCALING, dw, e[i].w) * sc.w;
      *reinterpret_cast<float4*>(out + (size_t)(tok0 + i) * DIM + c4) = o;
    }
  } else {
    // ---- tail path ----
    for (int i = 0; i < TOKENS_PER_BLOCK; ++i) {
      const int tok = tok0 + i;
      if (tok >= n_tokens) break;
      const int id = tokens[tok];
      const float* __restrict__ arow = lora_a + (size_t)id * RANK;
      const float4 ev = *reinterpret_cast<const float4*>(emb + (size_t)id * DIM + c4);
      float dx = 0.f, dy = 0.f, dz = 0.f, dw = 0.f;
#pragma unroll
      for (int k = 0; k < RANK; ++k) {
        const float a = arow[k];
        dx = fmaf(a, B[k].x, dx);
        dy = fmaf(a, B[k].y, dy);
        dz = fmaf(a, B[k].z, dz);
        dw = fmaf(a, B[k].w, dw);
      }
      float4 o;
      o.x = fmaf(SCALING, dx, ev.x) * sc.x;
      o.y = fmaf(SCALING, dy, ev.y) * sc.y;
      o.z = fmaf(SCALING, dz, ev.z) * sc.z;
      o.w = fmaf(SCALING, dw, ev.w) * sc.w;
      *reinterpret_cast<float4*>(out + (size_t)tok * DIM + c4) = o;
    }
  }
}

extern "C" void kernel_launch(void* const* d_in, const int* in_sizes, int n_in,
                              void* d_out, int out_size, void* d_ws, size_t ws_size,
                              hipStream_t stream) {
  const int*   tokens    = (const int*)d_in[0];    // [8,2048] int32
  const float* emb       = (const float*)d_in[1];  // [V, D]
  const float* lora_a    = (const float*)d_in[2];  // [V, R]
  const float* lora_b    = (const float*)d_in[3];  // [R, D]
  const float* magnitude = (const float*)d_in[4];  // [D]
  float* out = (float*)d_out;

  const int n_tokens = in_sizes[0];                // 16384

  float* partials = (float*)d_ws;                                  // P1_BLOCKS * DIM floats
  float* scale    = (float*)d_ws + (size_t)P1_BLOCKS * DIM;        // DIM floats

  dora_pass1<<<P1_BLOCKS, P1_THREADS, 0, stream>>>(emb, lora_a, lora_b, partials);
  dora_reduce<<<RED_BLOCKS, RED_THREADS, 0, stream>>>(partials, magnitude, scale);

  const int gather_blocks = (n_tokens + TOKENS_PER_BLOCK - 1) / TOKENS_PER_BLOCK;
  dora_gather<<<gather_blocks, G_THREADS, 0, stream>>>(tokens, emb, lora_a, lora_b,
                                                       scale, out, n_tokens);
}